// Round 13
// baseline (2368.184 us; speedup 1.0000x reference)
//
#include <hip/hip_runtime.h>
#include <stdint.h>

#define SS 64
#define BB 64
#define TT 100
#define HOPC 256
#define NFC 256
#define GCC 256
#define ICC 512
#define NC (1.0f/127.0f)
#define NBLK 64       // one block per chain
#define NTHR 512      // 8 waves: lane = (row, g), row=tid>>3, g=tid&7

// f16 weight arena offsets (in halves; same order as inputs 6..19)
#define OFF_FW     0
#define OFF_FWGLU  8192
#define OFF_G1IH   12288
#define OFF_G1HH   36864
#define OFF_GLU1   49152
#define OFF_G2IH   53248
#define OFF_G2HH   77824
#define OFF_GLU2   90112
#define OFF_G3IH   94208
#define OFF_G3HH   118784
#define OFF_GLU3   131072
#define OFF_SKIPD  135168
#define OFF_SKIPG  176128
#define OFF_OUT    192512
#define W_TOTAL    200704
#define XALL_F32   (TT * BB * HOPC)   // 1,638,400 floats
#define UG_FLOATS  ((size_t)400 * 64 * 704)   // 18,022,400 floats = 72.1 MB

typedef _Float16 f16;
typedef _Float16 h2 __attribute__((ext_vector_type(2)));
union U16 { uint4 u; h2 h[4]; };

#if __has_builtin(__builtin_amdgcn_fdot2)
#define FDOT2(a, b, c) __builtin_amdgcn_fdot2((a), (b), (c), false)
#else
#define FDOT2(a, b, c) ((c) + (float)(a)[0] * (float)(b)[0] + (float)(a)[1] * (float)(b)[1])
#endif

// ---------------- threefry2x32 core (Random123-KAT verified) ----------------
__device__ __forceinline__ uint32_t rotl32(uint32_t x, int r) {
    return (x << r) | (x >> (32 - r));
}

__device__ __forceinline__ void tf2x32(uint32_t k0, uint32_t k1, uint32_t c0, uint32_t c1,
                                       uint32_t& o0, uint32_t& o1) {
    uint32_t k2 = k0 ^ k1 ^ 0x1BD11BDAu;
    uint32_t x0 = c0 + k0, x1 = c1 + k1;
    x0 += x1; x1 = rotl32(x1, 13); x1 ^= x0;
    x0 += x1; x1 = rotl32(x1, 15); x1 ^= x0;
    x0 += x1; x1 = rotl32(x1, 26); x1 ^= x0;
    x0 += x1; x1 = rotl32(x1, 6);  x1 ^= x0;
    x0 += k1; x1 += k2 + 1u;
    x0 += x1; x1 = rotl32(x1, 17); x1 ^= x0;
    x0 += x1; x1 = rotl32(x1, 29); x1 ^= x0;
    x0 += x1; x1 = rotl32(x1, 16); x1 ^= x0;
    x0 += x1; x1 = rotl32(x1, 24); x1 ^= x0;
    x0 += k2; x1 += k0 + 2u;
    x0 += x1; x1 = rotl32(x1, 13); x1 ^= x0;
    x0 += x1; x1 = rotl32(x1, 15); x1 ^= x0;
    x0 += x1; x1 = rotl32(x1, 26); x1 ^= x0;
    x0 += x1; x1 = rotl32(x1, 6);  x1 ^= x0;
    x0 += k0; x1 += k1 + 3u;
    x0 += x1; x1 = rotl32(x1, 17); x1 ^= x0;
    x0 += x1; x1 = rotl32(x1, 29); x1 ^= x0;
    x0 += x1; x1 = rotl32(x1, 16); x1 ^= x0;
    x0 += x1; x1 = rotl32(x1, 24); x1 ^= x0;
    x0 += k1; x1 += k2 + 4u;
    x0 += x1; x1 = rotl32(x1, 13); x1 ^= x0;
    x0 += x1; x1 = rotl32(x1, 15); x1 ^= x0;
    x0 += x1; x1 = rotl32(x1, 26); x1 ^= x0;
    x0 += x1; x1 = rotl32(x1, 6);  x1 ^= x0;
    x0 += k2; x1 += k0 + 5u;
    o0 = x0; o1 = x1;
}

// jax_threefry_partitionable semantics: bits(m) = x0^x1 of block (0, m)
__device__ __forceinline__ float unifP(uint32_t k0, uint32_t k1, uint32_t m) {
    uint32_t o0, o1;
    tf2x32(k0, k1, 0u, m, o0, o1);
    uint32_t bits = o0 ^ o1;
    return __uint_as_float((bits >> 9) | 0x3f800000u) - 1.0f;
}

__device__ __forceinline__ float clipf(float v) { return fminf(1.0f, fmaxf(-1.0f, v)); }
__device__ __forceinline__ float noiseu(float v, float u) {
    return clipf(v + (u - 0.5f) * NC);
}
__device__ __forceinline__ float sigmf(float v) {
    return __fdividef(1.0f, 1.0f + __expf(-v));
}
__device__ __forceinline__ float tanhfast(float x) {
    float ax = fminf(fabsf(x), 15.0f);
    float e = __expf(2.0f * ax);
    float r = __fdividef(e - 1.0f, e + 1.0f);
    return copysignf(r, x);
}

// barrier WITHOUT the vmcnt(0) drain __syncthreads() would emit.
__device__ __forceinline__ void bar_lds() {
    asm volatile("s_waitcnt lgkmcnt(0)\n\ts_barrier" ::: "memory");
}

// ---------------- DPP 8-lane reduction (VALU-only, no DS pipe) --------------
__device__ __forceinline__ float red8dpp(float v) {
    int t;
    t = __builtin_amdgcn_update_dpp(0, __float_as_int(v), 0xB1, 0xF, 0xF, true);  // quad xor1
    v += __int_as_float(t);
    t = __builtin_amdgcn_update_dpp(0, __float_as_int(v), 0x4E, 0xF, 0xF, true);  // quad xor2
    v += __int_as_float(t);
    t = __builtin_amdgcn_update_dpp(0, __float_as_int(v), 0x141, 0xF, 0xF, true); // half-row mirror
    v += __int_as_float(t);
    return v;   // all 8 lanes of the group hold the sum
}

// ---------------- f16 dot helper ----------------
__device__ __forceinline__ float dotU(const U16& w, const U16& x, float acc) {
#pragma unroll
    for (int i = 0; i < 4; ++i) acc = FDOT2(w.h[i], x.h[i], acc);
    return acc;
}

// ---------------- register weight structs + loaders ----------------
struct WF1  { U16 w[2]; };                        // K=128, NR=1
struct WGRU { U16 wih[6]; U16 whh[3]; U16 glu; }; // 40 VGPRs
struct WSK  { U16 w[10]; };                       // K=320, NR=2
struct WSG  { U16 w[4]; };                        // K=128, NR=2

__device__ __forceinline__ void ldF1(const f16* W, int row, int g, WF1& r) {
    const f16* p = W + row * 128 + g * 16;
    r.w[0].u = *(const uint4*)p;
    r.w[1].u = *(const uint4*)(p + 8);
}
__device__ __forceinline__ void ldF2(const f16* W, int row, int g, U16& r) {
    r.u = *(const uint4*)(W + row * 64 + g * 8);
}
__device__ __forceinline__ void ldGRU(const f16* Wih, const f16* Whh, const f16* Glu,
                                      int row, int g, WGRU& r) {
#pragma unroll
    for (int j = 0; j < 3; ++j) {
        const f16* p = Wih + (row + 64 * j) * 128 + g * 16;
        r.wih[2 * j].u     = *(const uint4*)p;
        r.wih[2 * j + 1].u = *(const uint4*)(p + 8);
        r.whh[j].u = *(const uint4*)(Whh + (row + 64 * j) * 64 + g * 8);
    }
    r.glu.u = *(const uint4*)(Glu + row * 64 + g * 8);
}
__device__ __forceinline__ void ldSK(const f16* W, int row, int g, WSK& r) {
#pragma unroll
    for (int j = 0; j < 2; ++j) {
        const f16* p = W + (row + 64 * j) * 320 + g * 40;
#pragma unroll
        for (int i = 0; i < 5; ++i) r.w[5 * j + i].u = *(const uint4*)(p + 8 * i);
    }
}
__device__ __forceinline__ void ldSG(const f16* W, int row, int g, WSG& r) {
#pragma unroll
    for (int j = 0; j < 2; ++j) {
        const f16* p = W + (row + 64 * j) * 128 + g * 16;
        r.w[2 * j].u     = *(const uint4*)p;
        r.w[2 * j + 1].u = *(const uint4*)(p + 8);
    }
}

// opaque pin: makes the loaded values asm-defined -> cannot be rematerialized
__device__ __forceinline__ void pinU(U16& r) {
    asm volatile("" : "+v"(r.u.x), "+v"(r.u.y), "+v"(r.u.z), "+v"(r.u.w));
}

// ---------------- prep1: weight convert (blocks 0..783) | feature transpose
// (blocks 784..1039). Fuses two independent prologue kernels into one launch.
struct SrcW { const float* p[14]; };

__global__ __launch_bounds__(256) void fargan_prep1(
    SrcW s, f16* __restrict__ dst,
    const float* __restrict__ f, float* __restrict__ fT)
{
    __shared__ float L[64][104];
    const int bid = blockIdx.x;
    const int tid = threadIdx.x;
    if (bid < 784) {
        // ---- cvtw
        const int offs[15] = {0, 8192, 12288, 36864, 49152, 53248, 77824, 90112,
                              94208, 118784, 131072, 135168, 176128, 192512, 200704};
        int i = bid * 256 + tid;
        if (i >= W_TOTAL) return;
        int sgi = 0;
#pragma unroll
        for (int t = 1; t < 14; ++t) sgi += (i >= offs[t]);
        dst[i] = (f16)s.p[sgi][i - offs[sgi]];
    } else {
        // ---- tr: f[b][c][t] -> fT[t][b][c]
        int bb = bid - 784;
        int b = bb >> 2, c0 = (bb & 3) * 64;
        for (int e = tid; e < 6400; e += 256) {
            int r = e / 100, col = e - r * 100;
            L[r][col] = f[b * NFC * TT + (c0 + r) * TT + col];
        }
        __syncthreads();
        for (int e = tid; e < 6400; e += 256) {
            int t = e >> 6, c = e & 63;
            fT[(t * BB + b) * NFC + c0 + c] = L[c][t];
        }
    }
}

// ---------------- prep2: frame GEMM (blocks 0..799) | ugen (blocks 800..1199)
// Fuses the two heavy prologue kernels; they are independent and now fill the
// machine concurrently instead of serializing through two launches.
__global__ __launch_bounds__(256) void fargan_prep2(
    const float* __restrict__ fT, const float* __restrict__ gfeat,
    const float* __restrict__ W1, const float* __restrict__ ib1,
    const float* __restrict__ W2, const float* __restrict__ ib2,
    float* __restrict__ xall, float* __restrict__ ug)
{
    __shared__ __align__(16) float catL[8 * 516];
    __shared__ __align__(16) float zbL[8 * 516];
    __shared__ __align__(16) float Wt[64 * 68];
    __shared__ uint32_t kk[20];
    const int tid = threadIdx.x;

    if (blockIdx.x >= 800) {
        // ---- ugen: one block per idx
        const int idx = blockIdx.x - 800;
        if (tid < 10) {
            uint32_t f0, f1; tf2x32(0u, 1u, 0u, (uint32_t)idx, f0, f1);
            uint32_t A, Bv;  tf2x32(f0, f1, 0u, (uint32_t)tid, A, Bv);
            kk[2 * tid] = A; kk[2 * tid + 1] = Bv;
        }
        __syncthreads();
        float* ds = ug + (size_t)idx * 64 * 704;
        for (int c = 0; c < 64; ++c) {
            for (int j = tid; j < 704; j += 256) {
                int sl = j >> 6;
                int kx = (sl < 9) ? 2 * sl : 18;
                uint32_t m = (sl < 9) ? (uint32_t)(c * 64 + (j & 63))
                                      : (uint32_t)(c * 128 + (j - 576));
                ds[c * 704 + j] = unifP(kk[kx], kk[kx + 1], m);
            }
        }
        return;
    }

    // ---- frame: LDS-tiled fp32 GEMM (identical to r12 fargan_frame)
    const int t = blockIdx.x >> 3;
    const int q = blockIdx.x & 7;
    const int b = tid & 7;       // batch within tile
    const int nq = tid >> 3;     // 0..31

    for (int e = tid; e < 8 * 512; e += 256) {
        int bb = e >> 9, c = e & 511;
        float v = (c < NFC) ? fT[(t * BB + q * 8 + bb) * NFC + c]
                            : gfeat[(q * 8 + bb) * GCC + (c - NFC)];
        catL[bb * 516 + c] = v;
    }
    __syncthreads();

    // phase 1: zb = tanh(cat @ W1^T + b1)
    for (int n0 = 0; n0 < 512; n0 += 64) {
        float a0 = 0.f, a1 = 0.f;
        for (int k0 = 0; k0 < 512; k0 += 64) {
            for (int e = tid; e < 1024; e += 256) {
                int r = e >> 4, c4 = (e & 15) << 2;
                *(float4*)&Wt[r * 68 + c4] =
                    *(const float4*)&W1[(n0 + r) * ICC + k0 + c4];
            }
            __syncthreads();
#pragma unroll
            for (int kc = 0; kc < 16; ++kc) {
                float4 cv = *(const float4*)&catL[b * 516 + k0 + kc * 4];
                float4 w0 = *(const float4*)&Wt[nq * 68 + kc * 4];
                float4 w1 = *(const float4*)&Wt[(nq + 32) * 68 + kc * 4];
                a0 += w0.x * cv.x + w0.y * cv.y + w0.z * cv.z + w0.w * cv.w;
                a1 += w1.x * cv.x + w1.y * cv.y + w1.z * cv.z + w1.w * cv.w;
            }
            __syncthreads();
        }
        zbL[b * 516 + n0 + nq]      = tanhf(a0 + ib1[n0 + nq]);
        zbL[b * 516 + n0 + nq + 32] = tanhf(a1 + ib1[n0 + nq + 32]);
    }
    __syncthreads();

    // phase 2: xall = zb @ W2^T + b2
    for (int n0 = 0; n0 < 256; n0 += 64) {
        float a0 = 0.f, a1 = 0.f;
        for (int k0 = 0; k0 < 512; k0 += 64) {
            for (int e = tid; e < 1024; e += 256) {
                int r = e >> 4, c4 = (e & 15) << 2;
                *(float4*)&Wt[r * 68 + c4] =
                    *(const float4*)&W2[(n0 + r) * ICC + k0 + c4];
            }
            __syncthreads();
#pragma unroll
            for (int kc = 0; kc < 16; ++kc) {
                float4 cv = *(const float4*)&zbL[b * 516 + k0 + kc * 4];
                float4 w0 = *(const float4*)&Wt[nq * 68 + kc * 4];
                float4 w1 = *(const float4*)&Wt[(nq + 32) * 68 + kc * 4];
                a0 += w0.x * cv.x + w0.y * cv.y + w0.z * cv.z + w0.w * cv.w;
                a1 += w1.x * cv.x + w1.y * cv.y + w1.z * cv.z + w1.w * cv.w;
            }
            __syncthreads();
        }
        int B = t * BB + q * 8 + b;
        xall[B * HOPC + n0 + nq]      = a0 + ib2[n0 + nq];
        xall[B * HOPC + n0 + nq + 32] = a1 + ib2[n0 + nq + 32];
    }
}

// ---------------- sequential chain, pre-generated uniforms (v10, verified) --
__global__ __launch_bounds__(512) void fargan_seqpg(
    const float* __restrict__ xall, const f16* __restrict__ wh,
    const float* __restrict__ ug, float* __restrict__ outp)
{
    const int tid = threadIdx.x;
    const int row = tid >> 3;
    const int g = tid & 7;
    const int bg = blockIdx.x;          // chain id

    __shared__ __align__(16) f16 XH[128];          // xsub|s3 mirrors
    __shared__ __align__(16) f16 SKXH[320];        // g1|g2|g3|fw|prevN
    __shared__ __align__(16) f16 TWH[64], HNH[64];
    __shared__ __align__(16) f16 SPNH[128], SKVH[128];
    __shared__ __align__(16) f16 HH[2][3][64];     // GRU state f16 mirrors (ping-pong)
    __shared__ __align__(16) float Hf[2][3][64];   // GRU state fp32 (ping-pong)
    __shared__ __align__(16) float UNF[2][704];    // uniforms, double-buffered by idx&1

    // ---- one-time: register weights (pinned) + init
    WF1 rF1;  ldF1(wh + OFF_FW, row, g, rF1);
    U16 rF2;  ldF2(wh + OFF_FWGLU, row, g, rF2);
    WGRU rG1; ldGRU(wh + OFF_G1IH, wh + OFF_G1HH, wh + OFF_GLU1, row, g, rG1);
    WGRU rG2; ldGRU(wh + OFF_G2IH, wh + OFF_G2HH, wh + OFF_GLU2, row, g, rG2);
    WGRU rG3; ldGRU(wh + OFF_G3IH, wh + OFF_G3HH, wh + OFF_GLU3, row, g, rG3);
    WSG rSG;  ldSG(wh + OFF_SKIPG, row, g, rSG);
    WF1 rOUT; ldF1(wh + OFF_OUT, row, g, rOUT);

    pinU(rF1.w[0]); pinU(rF1.w[1]); pinU(rF2);
#pragma unroll
    for (int j = 0; j < 6; ++j) { pinU(rG1.wih[j]); pinU(rG2.wih[j]); pinU(rG3.wih[j]); }
#pragma unroll
    for (int j = 0; j < 3; ++j) { pinU(rG1.whh[j]); pinU(rG2.whh[j]); pinU(rG3.whh[j]); }
    pinU(rG1.glu); pinU(rG2.glu); pinU(rG3.glu);
#pragma unroll
    for (int j = 0; j < 4; ++j) pinU(rSG.w[j]);
    pinU(rOUT.w[0]); pinU(rOUT.w[1]);

    float prevO = 0.f, xs_old = 0.f;
    if (g == 0) {
#pragma unroll
        for (int i = 0; i < 3; ++i) { Hf[0][i][row] = 0.f; HH[0][i][row] = (f16)0.f; }
        XH[row] = (f16)0.f; XH[64 + row] = (f16)0.f;
    }

    // ---- prologue: uniforms for idx 0 from ug
    for (int j = tid; j < 704; j += NTHR)
        UNF[0][j] = ug[(size_t)bg * 704 + j];

    // ---- prologue: x prefetch for frame 0
    float xf0 = xall[(0 * BB + bg) * HOPC + 0 * SS + row];
    float xf1 = xall[(0 * BB + bg) * HOPC + 1 * SS + row];
    float xf2 = xall[(0 * BB + bg) * HOPC + 2 * SS + row];
    float xf3 = xall[(0 * BB + bg) * HOPC + 3 * SS + row];
    __syncthreads();

    for (int t = 0; t < TT; ++t) {
        // prefetch next frame's x (consumed 4..8 steps from now)
        const int tn = (t + 1 < TT) ? t + 1 : t;
        float xn0 = xall[(tn * BB + bg) * HOPC + 0 * SS + row];
        float xn1 = xall[(tn * BB + bg) * HOPC + 1 * SS + row];
        float xn2 = xall[(tn * BB + bg) * HOPC + 2 * SS + row];
        float xn3 = xall[(tn * BB + bg) * HOPC + 3 * SS + row];

        for (int s = 0; s < 4; ++s) {
            const int idx = t * 4 + s;
            const int p = idx & 1;       // ping-pong parity (H state AND UNF buffer)
            float gl0, gl1;              // next step's uniforms (global->reg->LDS)

            // ======== A (merged with prev OUT): tiny               [barrier 1]
            if (g == 0) {
                float u0 = UNF[p][row];
                float u1 = UNF[p][64 + row];
                float xv = (s == 0) ? xf0 : (s == 1) ? xf1 : (s == 2) ? xf2 : xf3;
                float xs = noiseu(xv, u0);
                XH[row] = (f16)xs; XH[64 + row] = (f16)xs_old; xs_old = xs;
                SKXH[256 + row] = (f16)noiseu(prevO, u1);
            }
            bar_lds();

            // ======== FW1 + issue uniform loads for idx+1          [barrier 2]
            float twv;
            {
                const int idn = (idx + 1 < 400) ? idx + 1 : 399;
                const float* gsrc = ug + ((size_t)idn * 64 + bg) * 704;
                gl0 = gsrc[tid];
                gl1 = (tid < 192) ? gsrc[512 + tid] : 0.f;

                U16 xa, xb;
                xa.u = *(const uint4*)&XH[g * 16];
                xb.u = *(const uint4*)&XH[g * 16 + 8];
                float a = dotU(rF1.w[0], xa, 0.f);
                a = dotU(rF1.w[1], xb, a);
                twv = tanhfast(red8dpp(a));
                if (g == 0) TWH[row] = (f16)twv;
            }
            bar_lds();

            // ======== FW2                                          [barrier 3]
            {
                U16 xa; xa.u = *(const uint4*)&TWH[g * 8];
                float a = red8dpp(dotU(rF2, xa, 0.f));
                if (g == 0) SKXH[192 + row] = (f16)noiseu(twv * sigmf(a), UNF[p][128 + row]);
            }
            bar_lds();

            // ======== GRU+GLU x3 (2 barriers each)
#define GRU_STEP(RG, XPTR, GI, UH, UG_, GOFF, EXTRA)                                        \
            {                                                                               \
                const f16* xin = (XPTR);                                                    \
                U16 xa, xb, xh;                                                             \
                xa.u = *(const uint4*)xin;                                                  \
                xb.u = *(const uint4*)(xin + 8);                                            \
                xh.u = *(const uint4*)&HH[p][GI][g * 8];                                    \
                EXTRA;                                                                      \
                float ai0 = 0, ai1 = 0, ai2 = 0, ah0 = 0, ah1 = 0, ah2 = 0;                 \
                ai0 = dotU(RG.wih[0], xa, ai0); ai0 = dotU(RG.wih[1], xb, ai0);             \
                ai1 = dotU(RG.wih[2], xa, ai1); ai1 = dotU(RG.wih[3], xb, ai1);             \
                ai2 = dotU(RG.wih[4], xa, ai2); ai2 = dotU(RG.wih[5], xb, ai2);             \
                ah0 = dotU(RG.whh[0], xh, ah0);                                             \
                ah1 = dotU(RG.whh[1], xh, ah1);                                             \
                ah2 = dotU(RG.whh[2], xh, ah2);                                             \
                ai0 = red8dpp(ai0); ai1 = red8dpp(ai1); ai2 = red8dpp(ai2);                 \
                ah0 = red8dpp(ah0); ah1 = red8dpp(ah1); ah2 = red8dpp(ah2);                 \
                float hold = Hf[p][GI][row];                                                \
                float r  = sigmf(ai0 + ah0);                                                \
                float z  = sigmf(ai1 + ah1);                                                \
                float nn = tanhfast(ai2 + r * ah2);                                         \
                float hnew = (1.f - z) * nn + z * hold;                                     \
                float hNv = noiseu(hnew, UNF[p][(UH) + row]);                               \
                if (g == 0) {                                                               \
                    Hf[p ^ 1][GI][row] = hnew;                                              \
                    HH[p ^ 1][GI][row] = (f16)hnew;                                         \
                    HNH[row] = (f16)hNv;                                                    \
                }                                                                           \
                bar_lds();                                                                  \
                U16 xg; xg.u = *(const uint4*)&HNH[g * 8];                                  \
                float ag = red8dpp(dotU(RG.glu, xg, 0.f));                                  \
                if (g == 0) SKXH[(GOFF) + row] =                                            \
                    (f16)noiseu(hNv * sigmf(ag), UNF[p][(UG_) + row]);                      \
            }                                                                               \
            bar_lds();

            // store next step's uniforms (loads issued at FW1, long done)
#define UNF_STORE do {                                                                      \
                UNF[p ^ 1][tid] = gl0;                                                      \
                if (tid < 192) UNF[p ^ 1][512 + tid] = gl1; } while (0)

            GRU_STEP(rG1, SKXH + 192 + g * 16, 0, 192, 256, 0, ((void)0))
            GRU_STEP(rG2, (g < 4 ? SKXH + g * 16 : SKXH + 256 + (g - 4) * 16), 1, 320, 384, 64, UNF_STORE)
            WSK rSK; ldSK(wh + OFF_SKIPD, row, g, rSK);   // prefetch skip_dense
            GRU_STEP(rG3, (g < 4 ? SKXH + 64 + g * 16 : SKXH + 256 + (g - 4) * 16), 2, 448, 512, 128, ((void)0))
#undef GRU_STEP
#undef UNF_STORE

            // ======== SKIP: spN = noise(tanh(skip_dense @ SKXH))   [barrier 10]
            float sp0, sp1;
            {
                U16 xs[5];
#pragma unroll
                for (int i = 0; i < 5; ++i) xs[i].u = *(const uint4*)&SKXH[g * 40 + 8 * i];
                float a0 = 0, a1 = 0;
#pragma unroll
                for (int i = 0; i < 5; ++i) {
                    a0 = dotU(rSK.w[i], xs[i], a0);
                    a1 = dotU(rSK.w[5 + i], xs[i], a1);
                }
                sp0 = noiseu(tanhfast(red8dpp(a0)), UNF[p][576 + row]);
                sp1 = noiseu(tanhfast(red8dpp(a1)), UNF[p][640 + row]);
                if (g == 0) { SPNH[row] = (f16)sp0; SPNH[64 + row] = (f16)sp1; }
            }
            bar_lds();

            // ======== SG: skip = spN * sigm(skip_glu @ spN)        [barrier 11]
            {
                U16 xa, xb;
                xa.u = *(const uint4*)&SPNH[g * 16];
                xb.u = *(const uint4*)&SPNH[g * 16 + 8];
                float a0 = dotU(rSG.w[0], xa, 0.f); a0 = dotU(rSG.w[1], xb, a0);
                float a1 = dotU(rSG.w[2], xa, 0.f); a1 = dotU(rSG.w[3], xb, a1);
                a0 = red8dpp(a0); a1 = red8dpp(a1);
                if (g == 0) {
                    SKVH[row]      = (f16)(sp0 * sigmf(a0));
                    SKVH[64 + row] = (f16)(sp1 * sigmf(a1));
                }
            }
            bar_lds();

            // ======== OUT: o = tanh(out_W @ skip)   [no barrier]
            {
                U16 xa, xb;
                xa.u = *(const uint4*)&SKVH[g * 16];
                xb.u = *(const uint4*)&SKVH[g * 16 + 8];
                float a = dotU(rOUT.w[0], xa, 0.f);
                a = dotU(rOUT.w[1], xb, a);
                float o = tanhfast(red8dpp(a));
                prevO = o;
                if (g == 0) outp[bg * (TT * HOPC) + t * HOPC + s * SS + row] = o;
            }
        }
        xf0 = xn0; xf1 = xn1; xf2 = xn2; xf3 = xn3;
    }
}

// ---------------- sequential chain, in-kernel threefry (v4 fallback) --------
__global__ __launch_bounds__(512) void fargan_seq(
    const float* __restrict__ xall, const f16* __restrict__ wh,
    float* __restrict__ outp)
{
    const int tid = threadIdx.x;
    const int row = tid >> 3;
    const int g = tid & 7;
    const int bg = blockIdx.x;          // chain id

    __shared__ __align__(16) f16 XH[128];
    __shared__ __align__(16) f16 SKXH[320];
    __shared__ __align__(16) f16 TWH[64], HNH[64];
    __shared__ __align__(16) f16 SPNH[128], SKVH[128];
    __shared__ __align__(16) f16 HH[2][3][64];
    __shared__ __align__(16) float Hf[2][3][64];
    __shared__ __align__(16) float UNF[2][704];
    __shared__ uint32_t KK[401][20];

    WF1 rF1;  ldF1(wh + OFF_FW, row, g, rF1);
    U16 rF2;  ldF2(wh + OFF_FWGLU, row, g, rF2);
    WGRU rG1; ldGRU(wh + OFF_G1IH, wh + OFF_G1HH, wh + OFF_GLU1, row, g, rG1);
    WGRU rG2; ldGRU(wh + OFF_G2IH, wh + OFF_G2HH, wh + OFF_GLU2, row, g, rG2);
    WGRU rG3; ldGRU(wh + OFF_G3IH, wh + OFF_G3HH, wh + OFF_GLU3, row, g, rG3);
    WSG rSG;  ldSG(wh + OFF_SKIPG, row, g, rSG);
    WF1 rOUT; ldF1(wh + OFF_OUT, row, g, rOUT);

    pinU(rF1.w[0]); pinU(rF1.w[1]); pinU(rF2);
#pragma unroll
    for (int j = 0; j < 6; ++j) { pinU(rG1.wih[j]); pinU(rG2.wih[j]); pinU(rG3.wih[j]); }
#pragma unroll
    for (int j = 0; j < 3; ++j) { pinU(rG1.whh[j]); pinU(rG2.whh[j]); pinU(rG3.whh[j]); }
    pinU(rG1.glu); pinU(rG2.glu); pinU(rG3.glu);
#pragma unroll
    for (int j = 0; j < 4; ++j) pinU(rSG.w[j]);
    pinU(rOUT.w[0]); pinU(rOUT.w[1]);

    float prevO = 0.f, xs_old = 0.f;
    if (g == 0) {
#pragma unroll
        for (int i = 0; i < 3; ++i) { Hf[0][i][row] = 0.f; HH[0][i][row] = (f16)0.f; }
        XH[row] = (f16)0.f; XH[64 + row] = (f16)0.f;
    }

    for (int e = tid; e < 4010; e += NTHR) {
        int ii = e / 10, ki = e - ii * 10;
        uint32_t f0, f1; tf2x32(0u, 1u, 0u, (uint32_t)ii, f0, f1);
        uint32_t A, Bv;  tf2x32(f0, f1, 0u, (uint32_t)ki, A, Bv);
        KK[ii][2 * ki] = A; KK[ii][2 * ki + 1] = Bv;
    }
    __syncthreads();

    for (int j = tid; j < 704; j += NTHR) {
        int sl = j >> 6;
        int kx = (sl < 9) ? 2 * sl : 18;
        uint32_t m = (sl < 9) ? (uint32_t)(bg * 64 + (j & 63))
                              : (uint32_t)(bg * 128 + (j - 576));
        UNF[0][j] = unifP(KK[0][kx], KK[0][kx + 1], m);
    }

    float xf0 = xall[(0 * BB + bg) * HOPC + 0 * SS + row];
    float xf1 = xall[(0 * BB + bg) * HOPC + 1 * SS + row];
    float xf2 = xall[(0 * BB + bg) * HOPC + 2 * SS + row];
    float xf3 = xall[(0 * BB + bg) * HOPC + 3 * SS + row];
    __syncthreads();

    for (int t = 0; t < TT; ++t) {
        const int tn = (t + 1 < TT) ? t + 1 : t;
        float xn0 = xall[(tn * BB + bg) * HOPC + 0 * SS + row];
        float xn1 = xall[(tn * BB + bg) * HOPC + 1 * SS + row];
        float xn2 = xall[(tn * BB + bg) * HOPC + 2 * SS + row];
        float xn3 = xall[(tn * BB + bg) * HOPC + 3 * SS + row];

        for (int s = 0; s < 4; ++s) {
            const int idx = t * 4 + s;
            const int p = idx & 1;

            if (g == 0) {
                float u0 = UNF[p][row];
                float u1 = UNF[p][64 + row];
                float xv = (s == 0) ? xf0 : (s == 1) ? xf1 : (s == 2) ? xf2 : xf3;
                float xs = noiseu(xv, u0);
                XH[row] = (f16)xs; XH[64 + row] = (f16)xs_old; xs_old = xs;
                SKXH[256 + row] = (f16)noiseu(prevO, u1);
            }
            bar_lds();

            float twv;
            {
                U16 xa, xb;
                xa.u = *(const uint4*)&XH[g * 16];
                xb.u = *(const uint4*)&XH[g * 16 + 8];
                float a = dotU(rF1.w[0], xa, 0.f);
                a = dotU(rF1.w[1], xb, a);
                twv = tanhfast(red8dpp(a));
                if (g == 0) TWH[row] = (f16)twv;
            }
            bar_lds();

            {
                U16 xa; xa.u = *(const uint4*)&TWH[g * 8];
                if (tid < 256) {
                    int kx = 2 * (tid >> 6);
                    UNF[p ^ 1][tid] = unifP(KK[idx + 1][kx], KK[idx + 1][kx + 1],
                                            (uint32_t)(bg * 64 + (tid & 63)));
                }
                float a = red8dpp(dotU(rF2, xa, 0.f));
                if (g == 0) SKXH[192 + row] = (f16)noiseu(twv * sigmf(a), UNF[p][128 + row]);
            }
            bar_lds();

#define GRU_STEP(RG, XPTR, GI, UH, UG_, GOFF, EXTRA)                                        \
            {                                                                               \
                const f16* xin = (XPTR);                                                    \
                U16 xa, xb, xh;                                                             \
                xa.u = *(const uint4*)xin;                                                  \
                xb.u = *(const uint4*)(xin + 8);                                            \
                xh.u = *(const uint4*)&HH[p][GI][g * 8];                                    \
                EXTRA;                                                                      \
                float ai0 = 0, ai1 = 0, ai2 = 0, ah0 = 0, ah1 = 0, ah2 = 0;                 \
                ai0 = dotU(RG.wih[0], xa, ai0); ai0 = dotU(RG.wih[1], xb, ai0);             \
                ai1 = dotU(RG.wih[2], xa, ai1); ai1 = dotU(RG.wih[3], xb, ai1);             \
                ai2 = dotU(RG.wih[4], xa, ai2); ai2 = dotU(RG.wih[5], xb, ai2);             \
                ah0 = dotU(RG.whh[0], xh, ah0);                                             \
                ah1 = dotU(RG.whh[1], xh, ah1);                                             \
                ah2 = dotU(RG.whh[2], xh, ah2);                                             \
                ai0 = red8dpp(ai0); ai1 = red8dpp(ai1); ai2 = red8dpp(ai2);                 \
                ah0 = red8dpp(ah0); ah1 = red8dpp(ah1); ah2 = red8dpp(ah2);                 \
                float hold = Hf[p][GI][row];                                                \
                float r  = sigmf(ai0 + ah0);                                                \
                float z  = sigmf(ai1 + ah1);                                                \
                float nn = tanhfast(ai2 + r * ah2);                                         \
                float hnew = (1.f - z) * nn + z * hold;                                     \
                float hNv = noiseu(hnew, UNF[p][(UH) + row]);                               \
                if (g == 0) {                                                               \
                    Hf[p ^ 1][GI][row] = hnew;                                              \
                    HH[p ^ 1][GI][row] = (f16)hnew;                                         \
                    HNH[row] = (f16)hNv;                                                    \
                }                                                                           \
                bar_lds();                                                                  \
                U16 xg; xg.u = *(const uint4*)&HNH[g * 8];                                  \
                float ag = red8dpp(dotU(RG.glu, xg, 0.f));                                  \
                if (g == 0) SKXH[(GOFF) + row] =                                            \
                    (f16)noiseu(hNv * sigmf(ag), UNF[p][(UG_) + row]);                      \
            }                                                                               \
            bar_lds();

#define NOISE_A2 do { if (tid >= 256) {                                                     \
                int kx = 2 * (tid >> 6);                                                    \
                UNF[p ^ 1][tid] = unifP(KK[idx + 1][kx], KK[idx + 1][kx + 1],               \
                                        (uint32_t)(bg * 64 + (tid & 63))); } } while (0)
#define NOISE_B do { int j2 = tid + 512; if (j2 < 704) {                                    \
                int kx = (j2 < 576) ? 16 : 18;                                              \
                uint32_t m2 = (j2 < 576) ? (uint32_t)(bg * 64 + (j2 & 63))                  \
                                         : (uint32_t)(bg * 128 + (j2 - 576));               \
                UNF[p ^ 1][j2] = unifP(KK[idx + 1][kx], KK[idx + 1][kx + 1], m2); } } while (0)

            GRU_STEP(rG1, SKXH + 192 + g * 16, 0, 192, 256, 0, NOISE_A2)
            GRU_STEP(rG2, (g < 4 ? SKXH + g * 16 : SKXH + 256 + (g - 4) * 16), 1, 320, 384, 64, NOISE_B)
            WSK rSK; ldSK(wh + OFF_SKIPD, row, g, rSK);
            GRU_STEP(rG3, (g < 4 ? SKXH + 64 + g * 16 : SKXH + 256 + (g - 4) * 16), 2, 448, 512, 128, ((void)0))
#undef GRU_STEP
#undef NOISE_A2
#undef NOISE_B

            float sp0, sp1;
            {
                U16 xs[5];
#pragma unroll
                for (int i = 0; i < 5; ++i) xs[i].u = *(const uint4*)&SKXH[g * 40 + 8 * i];
                float a0 = 0, a1 = 0;
#pragma unroll
                for (int i = 0; i < 5; ++i) {
                    a0 = dotU(rSK.w[i], xs[i], a0);
                    a1 = dotU(rSK.w[5 + i], xs[i], a1);
                }
                sp0 = noiseu(tanhfast(red8dpp(a0)), UNF[p][576 + row]);
                sp1 = noiseu(tanhfast(red8dpp(a1)), UNF[p][640 + row]);
                if (g == 0) { SPNH[row] = (f16)sp0; SPNH[64 + row] = (f16)sp1; }
            }
            bar_lds();

            {
                U16 xa, xb;
                xa.u = *(const uint4*)&SPNH[g * 16];
                xb.u = *(const uint4*)&SPNH[g * 16 + 8];
                float a0 = dotU(rSG.w[0], xa, 0.f); a0 = dotU(rSG.w[1], xb, a0);
                float a1 = dotU(rSG.w[2], xa, 0.f); a1 = dotU(rSG.w[3], xb, a1);
                a0 = red8dpp(a0); a1 = red8dpp(a1);
                if (g == 0) {
                    SKVH[row]      = (f16)(sp0 * sigmf(a0));
                    SKVH[64 + row] = (f16)(sp1 * sigmf(a1));
                }
            }
            bar_lds();

            {
                U16 xa, xb;
                xa.u = *(const uint4*)&SKVH[g * 16];
                xb.u = *(const uint4*)&SKVH[g * 16 + 8];
                float a = dotU(rOUT.w[0], xa, 0.f);
                a = dotU(rOUT.w[1], xb, a);
                float o = tanhfast(red8dpp(a));
                prevO = o;
                if (g == 0) outp[bg * (TT * HOPC) + t * HOPC + s * SS + row] = o;
            }
        }
        xf0 = xn0; xf1 = xn1; xf2 = xn2; xf3 = xn3;
    }
}

extern "C" void kernel_launch(void* const* d_in, const int* in_sizes, int n_in,
                              void* d_out, int out_size, void* d_ws, size_t ws_size,
                              hipStream_t stream) {
    const float* features = (const float*)d_in[0];
    const float* gfeat    = (const float*)d_in[1];
    const float* W1       = (const float*)d_in[2];
    const float* ib1      = (const float*)d_in[3];
    const float* W2       = (const float*)d_in[4];
    const float* ib2      = (const float*)d_in[5];

    float* xall = (float*)d_ws;                    // 6.55 MB
    float* fT   = xall + XALL_F32;                 // 6.55 MB
    f16*   wh   = (f16*)(fT + XALL_F32);           // 0.40 MB
    float* ug   = (float*)(wh + W_TOTAL);          // 72.1 MB (if ws permits)
    float* outp = (float*)d_out;

    const size_t need = (size_t)13508608 + UG_FLOATS * 4;
    const bool pregen = (ws_size >= need);

    SrcW sw;
    for (int i = 0; i < 14; ++i) sw.p[i] = (const float*)d_in[6 + i];

    // prep1: cvtw (784 blocks) | tr (256 blocks)
    hipLaunchKernelGGL(fargan_prep1, dim3(784 + 256), dim3(256), 0, stream,
                       sw, wh, features, fT);
    // prep2: frame (800 blocks) | ugen (400 blocks, only if pregen)
    hipLaunchKernelGGL(fargan_prep2, dim3(pregen ? 1200 : 800), dim3(256), 0, stream,
                       fT, gfeat, W1, ib1, W2, ib2, xall, ug);
    if (pregen) {
        hipLaunchKernelGGL(fargan_seqpg, dim3(NBLK), dim3(NTHR), 0, stream,
                           xall, wh, ug, outp);
    } else {
        hipLaunchKernelGGL(fargan_seq, dim3(NBLK), dim3(NTHR), 0, stream, xall, wh, outp);
    }
}